// Round 9
// baseline (255.102 us; speedup 1.0000x reference)
//
#include <hip/hip_runtime.h>

#define S_LEN 4096   // H*W
#define C_CH  256
#define D_CH  128
#define NIT   64     // t-iterations per block (t-range 2048, BT=32)
// softmax scale folded into exp2: lambda = (1/sqrt(256)) * log2(e)  [folded into Q at proj]
#define LAMBDA 0.09016844005555896f

typedef __attribute__((ext_vector_type(8)))  short short8;   // 8 x bf16 (4 VGPR)
typedef __attribute__((ext_vector_type(4)))  float f32x4;
typedef __attribute__((ext_vector_type(16))) float f32x16;

union PFrag { unsigned u[4]; short8 v; };

static __device__ __forceinline__ unsigned short f2bf(float x) {
    union { float f; unsigned u; } v; v.f = x;
    unsigned r = v.u + 0x7FFFu + ((v.u >> 16) & 1u);   // RNE
    return (unsigned short)(r >> 16);
}

static __device__ __forceinline__ void gload_lds16(const void* g, void* l) {
    __builtin_amdgcn_global_load_lds(
        (const __attribute__((address_space(1))) void*)g,
        (__attribute__((address_space(3))) void*)l, 16, 0, 0);
}

// ---------- kernel 1: x f32 -> xb bf16, layout [n][c][s] (V operand) ----------
__global__ void nlm_conv_kernel(const float* __restrict__ x, unsigned short* __restrict__ xb) {
    size_t base = ((size_t)blockIdx.x * 256 + threadIdx.x) * 4;
    float4 v = *reinterpret_cast<const float4*>(x + base);
    ushort4 b; b.x = f2bf(v.x); b.y = f2bf(v.y); b.z = f2bf(v.z); b.w = f2bf(v.w);
    *reinterpret_cast<ushort4*>(xb + base) = b;
}

// ---------- kernel 2: theta_w/phi_w f32 -> bf16, wb = [2][128][256] ----------
__global__ void nlm_wconv_kernel(const float* __restrict__ tw, const float* __restrict__ pw,
                                 unsigned short* __restrict__ wb) {
    int base = (blockIdx.x * 256 + threadIdx.x) * 4;
    const float* src = (base < 32768) ? (tw + base) : (pw + base - 32768);
    float4 v = *reinterpret_cast<const float4*>(src);
    ushort4 b; b.x = f2bf(v.x); b.y = f2bf(v.y); b.z = f2bf(v.z); b.w = f2bf(v.w);
    *reinterpret_cast<ushort4*>(wb + base) = b;
}

// ---------- kernel 3: projections Q[n][s][128] (pre-scaled by lambda), K[n][t][128] ----------
__launch_bounds__(256, 1)
__global__ void nlm_proj_kernel(const float* __restrict__ x,
                                const unsigned short* __restrict__ wb,
                                const float* __restrict__ tb, const float* __restrict__ pbias,
                                unsigned short* __restrict__ Qb, unsigned short* __restrict__ Kb) {
    const int n    = blockIdx.y;
    const int wave = threadIdx.x >> 6;
    const int lane = threadIdx.x & 63;
    const int sl   = lane & 15, g = lane >> 4;
    const int s0   = blockIdx.x * 64 + wave * 16;
    const float* xn = x + (size_t)n * C_CH * S_LEN;

    f32x4 acc[16];
    #pragma unroll
    for (int i = 0; i < 16; ++i) acc[i] = (f32x4){0.f, 0.f, 0.f, 0.f};

    #pragma unroll 1
    for (int cc = 0; cc < 8; ++cc) {
        short8 af;                                   // A[m=s][k=c]: lane m=sl, k=g*8+j
        #pragma unroll
        for (int j = 0; j < 8; ++j) {
            float v = xn[(size_t)(cc * 32 + g * 8 + j) * S_LEN + s0 + sl];
            af[j] = (short)f2bf(v);
        }
        #pragma unroll
        for (int t = 0; t < 16; ++t) {               // 0..7 theta tiles, 8..15 phi tiles
            const unsigned short* wp = wb + (size_t)(t >> 3) * (D_CH * C_CH)
                                          + (size_t)((t & 7) * 16 + sl) * C_CH + cc * 32 + g * 8;
            short8 bf = *reinterpret_cast<const short8*>(wp);
            acc[t] = __builtin_amdgcn_mfma_f32_16x16x32_bf16(af, bf, acc[t], 0, 0, 0);
        }
    }
    unsigned short* Qn = Qb + (size_t)n * S_LEN * D_CH;
    unsigned short* Kn = Kb + (size_t)n * S_LEN * D_CH;
    #pragma unroll
    for (int t = 0; t < 16; ++t) {
        const float bias = (t < 8 ? tb : pbias)[(t & 7) * 16 + sl];
        unsigned short* dst = (t < 8 ? Qn : Kn);
        #pragma unroll
        for (int r = 0; r < 4; ++r) {                // D row = g*4+r, col = sl
            float val = acc[t][r] + bias;
            if (t < 8) val *= LAMBDA;                // fold softmax scale into Q
            dst[(size_t)(s0 + g * 4 + r) * D_CH + (t & 7) * 16 + sl] = f2bf(val);
        }
    }
}

// ---------- kernel 4: flash attention, cross-iteration pipelined 32x32 waves ----------
// 256 blocks = 4 n x 2 t-half x 32 s-blocks(128 s). 4 waves x 32 q-rows each.
// Per iter: ONE barrier; stage K(it+1) [2-buf] + V(it+2) [3-buf]; QK(it) MFMAs;
// PV(it-1) MFMAs from register V/P (independent -> fills MFMA pipe while exp waits);
// exp(it) -> P-frags in reg (cvt_pk+permlane32_swap); vread V(it)->regs; vmcnt(4).
__launch_bounds__(256, 2)
__global__ void nlm_attn_kernel(const unsigned short* __restrict__ Qb,
                                const unsigned short* __restrict__ Kb,
                                const unsigned short* __restrict__ xb,
                                float* __restrict__ part0, float* __restrict__ part1,
                                float* __restrict__ lbuf) {
    // XCD swizzle: 256 blocks; 32 consecutive newb (one (n,th) group) per XCD.
    const int sid  = blockIdx.x;
    const int newb = (sid & 7) * 32 + (sid >> 3);
    const int n    = newb >> 6;
    const int th   = (newb >> 5) & 1;
    const int sb   = newb & 31;
    const int wave = threadIdx.x >> 6;
    const int lane = threadIdx.x & 63;
    const int l31  = lane & 31;
    const int h    = lane >> 5;
    const int s0   = sb * 128 + wave * 32;           // this wave's 32 q-rows
    const int tbase = th * 2048;

    __shared__ unsigned short Klds[2][32 * 128];     // [t-local][d], chunk-XOR swizzled
    __shared__ unsigned short Vlds[3][256 * 32];     // [c][t-local], chunk-XOR swizzled

    const unsigned short* Qn = Qb + (size_t)n * S_LEN * D_CH;
    const unsigned short* Kn = Kb + (size_t)n * S_LEN * D_CH;
    const unsigned short* xn = xb + (size_t)n * C_CH * S_LEN;

    // Q fragments (B operand): lane (s=l31, h): d = ks*16 + h*8 + j
    short8 qf[8];
    #pragma unroll
    for (int ks = 0; ks < 8; ++ks)
        qf[ks] = *reinterpret_cast<const short8*>(Qn + (size_t)(s0 + l31) * D_CH + ks * 16 + h * 8);

    f32x16 oacc[8];                                  // O^T: c-block cb*32.., s = s0+l31
    #pragma unroll
    for (int i = 0; i < 8; ++i)
        #pragma unroll
        for (int r = 0; r < 16; ++r) oacc[i][r] = 0.f;
    float lsum = 0.f;                                // per-lane partial row sum
    short8 vreg[16];                                 // V(it) fragments (read at end of iter it)

    auto kstage = [&](int it, int slot) {            // 32 rows x 256B, 2 insts/wave
        const int t0 = tbase + it * 32;
        #pragma unroll
        for (int i = 0; i < 2; ++i) {
            const int rl = wave * 8 + i * 4 + (lane >> 4);
            const int ch = (lane & 15) ^ (rl & 7);   // LDS[r][q] = G[t0+r][q^(r&7)]
            gload_lds16(Kn + (size_t)(t0 + rl) * D_CH + ch * 8,
                        &Klds[slot][(wave * 8 + i * 4) * 128]);
        }
    };
    auto vstage = [&](int it, int slot) {            // 256 rows x 64B, 4 insts/wave
        const int t0 = tbase + it * 32;
        #pragma unroll
        for (int i = 0; i < 4; ++i) {
            const int row = wave * 64 + i * 16 + (lane >> 2);
            const int ch = (lane & 3) ^ ((row >> 1) & 3);
            gload_lds16(xn + (size_t)row * S_LEN + t0 + ch * 8,
                        &Vlds[slot][(wave * 64 + i * 16) * 32]);
        }
    };

    // ---- one pipelined iteration: uses paU (P of it-1), builds paM (P of it) ----
    auto body = [&](int it, PFrag& paU0, PFrag& paU1, PFrag& paM0, PFrag& paM1) {
        __builtin_amdgcn_s_barrier();                // iter-it fence: K(it),V(it) landed;
        __builtin_amdgcn_sched_barrier(0);           // buffers (it+1)%2,(it+2)%3 free
        kstage(it + 1, (it + 1) & 1);                // OOB-safe past NIT (lands in ws)
        vstage(it + 2, (it + 2) % 3);

        // ---- QK(it): S^T[t][s] = K_tile * Q^T, 2 accumulator chains ----
        const int kslot = it & 1;
        f32x16 sa, sb2;
        #pragma unroll
        for (int r = 0; r < 16; ++r) { sa[r] = 0.f; sb2[r] = 0.f; }
        #pragma unroll
        for (int ks = 0; ks < 4; ++ks) {             // A: lane (t=l31,h): d=ks*16+h*8+j
            const int ch = (ks * 2 + h) ^ (l31 & 7);
            short8 kf = *reinterpret_cast<const short8*>(&Klds[kslot][l31 * 128 + ch * 8]);
            sa = __builtin_amdgcn_mfma_f32_32x32x16_bf16(kf, qf[ks], sa, 0, 0, 0);
        }
        #pragma unroll
        for (int ks = 4; ks < 8; ++ks) {
            const int ch = (ks * 2 + h) ^ (l31 & 7);
            short8 kf = *reinterpret_cast<const short8*>(&Klds[kslot][l31 * 128 + ch * 8]);
            sb2 = __builtin_amdgcn_mfma_f32_32x32x16_bf16(kf, qf[ks], sb2, 0, 0, 0);
        }

        // ---- PV(it-1): independent of QK -> fills MFMA pipe while QK results land ----
        if (it > 0) {
            #pragma unroll
            for (int cb = 0; cb < 8; ++cb) {
                oacc[cb] = __builtin_amdgcn_mfma_f32_32x32x16_bf16(vreg[cb * 2],     paU0.v, oacc[cb], 0, 0, 0);
                oacc[cb] = __builtin_amdgcn_mfma_f32_32x32x16_bf16(vreg[cb * 2 + 1], paU1.v, oacc[cb], 0, 0, 0);
            }
        }

        // ---- exp (no max; lambda pre-folded into Q; scores O(0.03) in exp2 units) ----
        float p[16];
        float rs = 0.f;
        #pragma unroll
        for (int r = 0; r < 16; ++r) {
            p[r] = __builtin_amdgcn_exp2f(sa[r] + sb2[r]);
            rs += p[r];
        }
        lsum += rs;

        // ---- P -> bf16 B-fragments in-register (cvt_pk + permlane32_swap) ----
        unsigned W0, W1, W2, W3, W4, W5, W6, W7;
        asm("v_cvt_pk_bf16_f32 %0, %1, %2" : "=v"(W0) : "v"(p[0]),  "v"(p[1]));
        asm("v_cvt_pk_bf16_f32 %0, %1, %2" : "=v"(W1) : "v"(p[2]),  "v"(p[3]));
        asm("v_cvt_pk_bf16_f32 %0, %1, %2" : "=v"(W2) : "v"(p[4]),  "v"(p[5]));
        asm("v_cvt_pk_bf16_f32 %0, %1, %2" : "=v"(W3) : "v"(p[6]),  "v"(p[7]));
        asm("v_cvt_pk_bf16_f32 %0, %1, %2" : "=v"(W4) : "v"(p[8]),  "v"(p[9]));
        asm("v_cvt_pk_bf16_f32 %0, %1, %2" : "=v"(W5) : "v"(p[10]), "v"(p[11]));
        asm("v_cvt_pk_bf16_f32 %0, %1, %2" : "=v"(W6) : "v"(p[12]), "v"(p[13]));
        asm("v_cvt_pk_bf16_f32 %0, %1, %2" : "=v"(W7) : "v"(p[14]), "v"(p[15]));
        asm("v_permlane32_swap_b32 %0, %1" : "+v"(W0), "+v"(W2));
        asm("v_permlane32_swap_b32 %0, %1" : "+v"(W1), "+v"(W3));
        asm("v_permlane32_swap_b32 %0, %1" : "+v"(W4), "+v"(W6));
        asm("v_permlane32_swap_b32 %0, %1" : "+v"(W5), "+v"(W7));
        paM0.u[0] = W0; paM0.u[1] = W1; paM0.u[2] = W2; paM0.u[3] = W3;
        paM1.u[0] = W4; paM1.u[1] = W5; paM1.u[2] = W6; paM1.u[3] = W7;

        // ---- vread V(it) -> registers for next iter's PV ----
        const int vslot = it % 3;
        #pragma unroll
        for (int cb = 0; cb < 8; ++cb) {
            const int c = cb * 32 + l31;
            const int ch0 = (0 + h) ^ ((c >> 1) & 3);
            const int ch1 = (2 + h) ^ ((c >> 1) & 3);
            vreg[cb * 2]     = *reinterpret_cast<const short8*>(&Vlds[vslot][c * 32 + ch0 * 8]);
            vreg[cb * 2 + 1] = *reinterpret_cast<const short8*>(&Vlds[vslot][c * 32 + ch1 * 8]);
        }

        // drain K(it+1)+V(it+1) (keep V(it+2)'s 4) -> next barrier guarantees them landed
        asm volatile("s_waitcnt vmcnt(4)" ::: "memory");
        __builtin_amdgcn_sched_barrier(0);
    };

    // prologue: K(0), V(0), V(1); drain K(0)+V(0), keep V(1) in flight
    kstage(0, 0); vstage(0, 0); vstage(1, 1);
    asm volatile("s_waitcnt vmcnt(4)" ::: "memory");

    PFrag paA0, paA1, paB0, paB1;
    paA0.u[0] = paA0.u[1] = paA0.u[2] = paA0.u[3] = 0;
    paA1 = paA0; paB0 = paA0; paB1 = paA0;

    #pragma unroll 1
    for (int io = 0; io < NIT / 2; ++io) {
        body(io * 2,     paA0, paA1, paB0, paB1);
        body(io * 2 + 1, paB0, paB1, paA0, paA1);
    }

    // ---- epilogue: PV(NIT-1) from registers, reduce lsum, store partials ----
    asm volatile("s_waitcnt vmcnt(0)" ::: "memory");
    #pragma unroll
    for (int cb = 0; cb < 8; ++cb) {
        oacc[cb] = __builtin_amdgcn_mfma_f32_32x32x16_bf16(vreg[cb * 2],     paA0.v, oacc[cb], 0, 0, 0);
        oacc[cb] = __builtin_amdgcn_mfma_f32_32x32x16_bf16(vreg[cb * 2 + 1], paA1.v, oacc[cb], 0, 0, 0);
    }
    float lt = lsum + __shfl_xor(lsum, 32);          // full row sum for this t-half
    float* dst = (th == 0) ? part0 : part1;
    if (lane < 32) lbuf[th * 16384 + n * 4096 + s0 + lane] = lt;
    float* on = dst + (size_t)n * C_CH * S_LEN;
    #pragma unroll
    for (int cb = 0; cb < 8; ++cb) {
        #pragma unroll
        for (int r = 0; r < 16; ++r) {
            const int c = cb * 32 + (r & 3) + 8 * (r >> 2) + 4 * h;
            on[(size_t)c * S_LEN + s0 + l31] = oacc[cb][r];
        }
    }
}

// ---------- kernel 5: combine t-halves: out = (p0 + p1) / (l0 + l1) ----------
__global__ void nlm_combine_kernel(float* __restrict__ out, const float* __restrict__ part1,
                                   const float* __restrict__ lbuf) {
    const size_t e0 = ((size_t)blockIdx.x * 256 + threadIdx.x) * 4;
    const int n = (int)(e0 >> 20);
    const int s = (int)(e0 & 4095);
    float4 o0 = *reinterpret_cast<const float4*>(out + e0);
    float4 o1 = *reinterpret_cast<const float4*>(part1 + e0);
    float4 l0 = *reinterpret_cast<const float4*>(lbuf + n * 4096 + s);
    float4 l1 = *reinterpret_cast<const float4*>(lbuf + 16384 + n * 4096 + s);
    float4 r;
    r.x = (o0.x + o1.x) / (l0.x + l1.x);
    r.y = (o0.y + o1.y) / (l0.y + l1.y);
    r.z = (o0.z + o1.z) / (l0.z + l1.z);
    r.w = (o0.w + o1.w) / (l0.w + l1.w);
    *reinterpret_cast<float4*>(out + e0) = r;
}

extern "C" void kernel_launch(void* const* d_in, const int* in_sizes, int n_in,
                              void* d_out, int out_size, void* d_ws, size_t ws_size,
                              hipStream_t stream) {
    const float* x  = (const float*)d_in[0];
    const float* tw = (const float*)d_in[1];
    const float* tb = (const float*)d_in[2];
    const float* pw = (const float*)d_in[3];
    const float* pb = (const float*)d_in[4];
    float* out = (float*)d_out;

    char* ws = (char*)d_ws;
    unsigned short* xb = (unsigned short*)(ws);               //  8,388,608 B
    unsigned short* Qb = (unsigned short*)(ws + 8388608);     //  4,194,304 B
    unsigned short* Kb = (unsigned short*)(ws + 12582912);    //  4,194,304 B
    unsigned short* wb = (unsigned short*)(ws + 16777216);    //    131,072 B
    float*          lb = (float*)(ws + 16908288);             //    131,072 B
    float*          p1 = (float*)(ws + 17039360);             // 16,777,216 B

    nlm_conv_kernel<<<4096, 256, 0, stream>>>(x, xb);
    nlm_wconv_kernel<<<64, 256, 0, stream>>>(tw, pw, wb);
    nlm_proj_kernel<<<dim3(64, 4), 256, 0, stream>>>(x, wb, tb, pb, Qb, Kb);
    nlm_attn_kernel<<<256, 256, 0, stream>>>(Qb, Kb, xb, out, p1, lb);
    nlm_combine_kernel<<<4096, 256, 0, stream>>>(out, p1, lb);
}

// Round 10
// 118.194 us; speedup vs baseline: 2.1583x; 2.1583x over previous
//
#include <hip/hip_runtime.h>

#define S_LEN 4096   // H*W
#define C_CH  256
#define D_CH  128
#define NIT   64     // t-iterations per block (t-range 2048, BT=32)
// softmax scale folded into exp2: lambda = (1/sqrt(256)) * log2(e)  [folded into Q at proj]
#define LAMBDA 0.09016844005555896f

typedef __attribute__((ext_vector_type(8)))  short short8;   // 8 x bf16 (4 VGPR)
typedef __attribute__((ext_vector_type(4)))  float f32x4;
typedef __attribute__((ext_vector_type(16))) float f32x16;

union PFrag { unsigned u[4]; short8 v; };

static __device__ __forceinline__ unsigned short f2bf(float x) {
    union { float f; unsigned u; } v; v.f = x;
    unsigned r = v.u + 0x7FFFu + ((v.u >> 16) & 1u);   // RNE
    return (unsigned short)(r >> 16);
}

static __device__ __forceinline__ void gload_lds16(const void* g, void* l) {
    __builtin_amdgcn_global_load_lds(
        (const __attribute__((address_space(1))) void*)g,
        (__attribute__((address_space(3))) void*)l, 16, 0, 0);
}

// ---------- kernel 1: x f32 -> xb bf16, layout [n][c][s] (V operand) ----------
__global__ void nlm_conv_kernel(const float* __restrict__ x, unsigned short* __restrict__ xb) {
    size_t base = ((size_t)blockIdx.x * 256 + threadIdx.x) * 4;
    float4 v = *reinterpret_cast<const float4*>(x + base);
    ushort4 b; b.x = f2bf(v.x); b.y = f2bf(v.y); b.z = f2bf(v.z); b.w = f2bf(v.w);
    *reinterpret_cast<ushort4*>(xb + base) = b;
}

// ---------- kernel 2: theta_w/phi_w f32 -> bf16, wb = [2][128][256] ----------
__global__ void nlm_wconv_kernel(const float* __restrict__ tw, const float* __restrict__ pw,
                                 unsigned short* __restrict__ wb) {
    int base = (blockIdx.x * 256 + threadIdx.x) * 4;
    const float* src = (base < 32768) ? (tw + base) : (pw + base - 32768);
    float4 v = *reinterpret_cast<const float4*>(src);
    ushort4 b; b.x = f2bf(v.x); b.y = f2bf(v.y); b.z = f2bf(v.z); b.w = f2bf(v.w);
    *reinterpret_cast<ushort4*>(wb + base) = b;
}

// ---------- kernel 3: projections Q[n][s][128] (pre-scaled by lambda), K[n][t][128] ----------
__launch_bounds__(256, 1)
__global__ void nlm_proj_kernel(const float* __restrict__ x,
                                const unsigned short* __restrict__ wb,
                                const float* __restrict__ tb, const float* __restrict__ pbias,
                                unsigned short* __restrict__ Qb, unsigned short* __restrict__ Kb) {
    const int n    = blockIdx.y;
    const int wave = threadIdx.x >> 6;
    const int lane = threadIdx.x & 63;
    const int sl   = lane & 15, g = lane >> 4;
    const int s0   = blockIdx.x * 64 + wave * 16;
    const float* xn = x + (size_t)n * C_CH * S_LEN;

    f32x4 acc[16];
    #pragma unroll
    for (int i = 0; i < 16; ++i) acc[i] = (f32x4){0.f, 0.f, 0.f, 0.f};

    #pragma unroll 1
    for (int cc = 0; cc < 8; ++cc) {
        short8 af;                                   // A[m=s][k=c]: lane m=sl, k=g*8+j
        #pragma unroll
        for (int j = 0; j < 8; ++j) {
            float v = xn[(size_t)(cc * 32 + g * 8 + j) * S_LEN + s0 + sl];
            af[j] = (short)f2bf(v);
        }
        #pragma unroll
        for (int t = 0; t < 16; ++t) {               // 0..7 theta tiles, 8..15 phi tiles
            const unsigned short* wp = wb + (size_t)(t >> 3) * (D_CH * C_CH)
                                          + (size_t)((t & 7) * 16 + sl) * C_CH + cc * 32 + g * 8;
            short8 bf = *reinterpret_cast<const short8*>(wp);
            acc[t] = __builtin_amdgcn_mfma_f32_16x16x32_bf16(af, bf, acc[t], 0, 0, 0);
        }
    }
    unsigned short* Qn = Qb + (size_t)n * S_LEN * D_CH;
    unsigned short* Kn = Kb + (size_t)n * S_LEN * D_CH;
    #pragma unroll
    for (int t = 0; t < 16; ++t) {
        const float bias = (t < 8 ? tb : pbias)[(t & 7) * 16 + sl];
        unsigned short* dst = (t < 8 ? Qn : Kn);
        #pragma unroll
        for (int r = 0; r < 4; ++r) {                // D row = g*4+r, col = sl
            float val = acc[t][r] + bias;
            if (t < 8) val *= LAMBDA;                // fold softmax scale into Q
            dst[(size_t)(s0 + g * 4 + r) * D_CH + (t & 7) * 16 + sl] = f2bf(val);
        }
    }
}

// ---------- kernel 4: flash attention, cross-iteration pipelined 32x32 waves ----------
// 256 blocks (1/CU) = 4 n x 2 t-half x 32 s-blocks(128 s). 4 waves x 32 q-rows each.
// Per iter: ONE barrier; stage K(it+1) [2-buf] + V(it+2) [3-buf]; QK(it) MFMAs;
// PV(it-1) MFMAs from register V/P (independent -> fills MFMA pipe while exp waits);
// exp(it) -> P-frags in reg (cvt_pk+permlane32_swap); vread V(it)->regs; vmcnt(4).
// launch_bounds(256,1): 512-reg budget, ~330 live regs -> NO SPILL (r9's 285MB
// WRITE_SIZE was scratch spill from the (256,2) cap; grid is 1 block/CU anyway).
__launch_bounds__(256, 1)
__global__ void nlm_attn_kernel(const unsigned short* __restrict__ Qb,
                                const unsigned short* __restrict__ Kb,
                                const unsigned short* __restrict__ xb,
                                float* __restrict__ part0, float* __restrict__ part1,
                                float* __restrict__ lbuf) {
    // XCD swizzle: 256 blocks; 32 consecutive newb (one (n,th) group) per XCD.
    const int sid  = blockIdx.x;
    const int newb = (sid & 7) * 32 + (sid >> 3);
    const int n    = newb >> 6;
    const int th   = (newb >> 5) & 1;
    const int sb   = newb & 31;
    const int wave = threadIdx.x >> 6;
    const int lane = threadIdx.x & 63;
    const int l31  = lane & 31;
    const int h    = lane >> 5;
    const int s0   = sb * 128 + wave * 32;           // this wave's 32 q-rows
    const int tbase = th * 2048;

    __shared__ unsigned short Klds[2][32 * 128];     // [t-local][d], chunk-XOR swizzled
    __shared__ unsigned short Vlds[3][256 * 32];     // [c][t-local], chunk-XOR swizzled

    const unsigned short* Qn = Qb + (size_t)n * S_LEN * D_CH;
    const unsigned short* Kn = Kb + (size_t)n * S_LEN * D_CH;
    const unsigned short* xn = xb + (size_t)n * C_CH * S_LEN;

    // Q fragments (B operand): lane (s=l31, h): d = ks*16 + h*8 + j
    short8 qf[8];
    #pragma unroll
    for (int ks = 0; ks < 8; ++ks)
        qf[ks] = *reinterpret_cast<const short8*>(Qn + (size_t)(s0 + l31) * D_CH + ks * 16 + h * 8);

    f32x16 oacc[8];                                  // O^T: c-block cb*32.., s = s0+l31
    #pragma unroll
    for (int i = 0; i < 8; ++i)
        #pragma unroll
        for (int r = 0; r < 16; ++r) oacc[i][r] = 0.f;
    float lsum = 0.f;                                // per-lane partial row sum
    short8 vreg[16];                                 // V(it) fragments (read at end of iter it)

    auto kstage = [&](int itv, int slot) {           // 32 rows x 256B, 2 insts/wave
        const int it = itv < NIT ? itv : NIT - 1;    // clamp: tail stages dup tile (unread)
        const int t0 = tbase + it * 32;
        #pragma unroll
        for (int i = 0; i < 2; ++i) {
            const int rl = wave * 8 + i * 4 + (lane >> 4);
            const int ch = (lane & 15) ^ (rl & 7);   // LDS[r][q] = G[t0+r][q^(r&7)]
            gload_lds16(Kn + (size_t)(t0 + rl) * D_CH + ch * 8,
                        &Klds[slot][(wave * 8 + i * 4) * 128]);
        }
    };
    auto vstage = [&](int itv, int slot) {           // 256 rows x 64B, 4 insts/wave
        const int it = itv < NIT ? itv : NIT - 1;
        const int t0 = tbase + it * 32;
        #pragma unroll
        for (int i = 0; i < 4; ++i) {
            const int row = wave * 64 + i * 16 + (lane >> 2);
            const int ch = (lane & 3) ^ ((row >> 1) & 3);
            gload_lds16(xn + (size_t)row * S_LEN + t0 + ch * 8,
                        &Vlds[slot][(wave * 64 + i * 16) * 32]);
        }
    };

    // ---- one pipelined iteration: uses paU (P of it-1), builds paM (P of it) ----
    auto body = [&](int it, PFrag& paU0, PFrag& paU1, PFrag& paM0, PFrag& paM1) {
        __builtin_amdgcn_s_barrier();                // iter-it fence: K(it),V(it) landed;
        __builtin_amdgcn_sched_barrier(0);           // buffers (it+1)%2,(it+2)%3 free
        kstage(it + 1, (it + 1) & 1);
        vstage(it + 2, (it + 2) % 3);

        // ---- QK(it): S^T[t][s] = K_tile * Q^T, 2 accumulator chains ----
        const int kslot = it & 1;
        f32x16 sa, sb2;
        #pragma unroll
        for (int r = 0; r < 16; ++r) { sa[r] = 0.f; sb2[r] = 0.f; }
        #pragma unroll
        for (int ks = 0; ks < 4; ++ks) {             // A: lane (t=l31,h): d=ks*16+h*8+j
            const int ch = (ks * 2 + h) ^ (l31 & 7);
            short8 kf = *reinterpret_cast<const short8*>(&Klds[kslot][l31 * 128 + ch * 8]);
            sa = __builtin_amdgcn_mfma_f32_32x32x16_bf16(kf, qf[ks], sa, 0, 0, 0);
        }
        #pragma unroll
        for (int ks = 4; ks < 8; ++ks) {
            const int ch = (ks * 2 + h) ^ (l31 & 7);
            short8 kf = *reinterpret_cast<const short8*>(&Klds[kslot][l31 * 128 + ch * 8]);
            sb2 = __builtin_amdgcn_mfma_f32_32x32x16_bf16(kf, qf[ks], sb2, 0, 0, 0);
        }

        // ---- PV(it-1): independent of QK -> fills MFMA pipe while QK results land ----
        if (it > 0) {
            #pragma unroll
            for (int cb = 0; cb < 8; ++cb) {
                oacc[cb] = __builtin_amdgcn_mfma_f32_32x32x16_bf16(vreg[cb * 2],     paU0.v, oacc[cb], 0, 0, 0);
                oacc[cb] = __builtin_amdgcn_mfma_f32_32x32x16_bf16(vreg[cb * 2 + 1], paU1.v, oacc[cb], 0, 0, 0);
            }
        }

        // ---- exp (no max; lambda pre-folded into Q) ----
        float p[16];
        float rs = 0.f;
        #pragma unroll
        for (int r = 0; r < 16; ++r) {
            p[r] = __builtin_amdgcn_exp2f(sa[r] + sb2[r]);
            rs += p[r];
        }
        lsum += rs;

        // ---- P -> bf16 B-fragments in-register (cvt_pk + permlane32_swap) ----
        unsigned W0, W1, W2, W3, W4, W5, W6, W7;
        asm("v_cvt_pk_bf16_f32 %0, %1, %2" : "=v"(W0) : "v"(p[0]),  "v"(p[1]));
        asm("v_cvt_pk_bf16_f32 %0, %1, %2" : "=v"(W1) : "v"(p[2]),  "v"(p[3]));
        asm("v_cvt_pk_bf16_f32 %0, %1, %2" : "=v"(W2) : "v"(p[4]),  "v"(p[5]));
        asm("v_cvt_pk_bf16_f32 %0, %1, %2" : "=v"(W3) : "v"(p[6]),  "v"(p[7]));
        asm("v_cvt_pk_bf16_f32 %0, %1, %2" : "=v"(W4) : "v"(p[8]),  "v"(p[9]));
        asm("v_cvt_pk_bf16_f32 %0, %1, %2" : "=v"(W5) : "v"(p[10]), "v"(p[11]));
        asm("v_cvt_pk_bf16_f32 %0, %1, %2" : "=v"(W6) : "v"(p[12]), "v"(p[13]));
        asm("v_cvt_pk_bf16_f32 %0, %1, %2" : "=v"(W7) : "v"(p[14]), "v"(p[15]));
        asm("v_permlane32_swap_b32 %0, %1" : "+v"(W0), "+v"(W2));
        asm("v_permlane32_swap_b32 %0, %1" : "+v"(W1), "+v"(W3));
        asm("v_permlane32_swap_b32 %0, %1" : "+v"(W4), "+v"(W6));
        asm("v_permlane32_swap_b32 %0, %1" : "+v"(W5), "+v"(W7));
        paM0.u[0] = W0; paM0.u[1] = W1; paM0.u[2] = W2; paM0.u[3] = W3;
        paM1.u[0] = W4; paM1.u[1] = W5; paM1.u[2] = W6; paM1.u[3] = W7;

        // ---- vread V(it) -> registers for next iter's PV ----
        const int vslot = it % 3;
        #pragma unroll
        for (int cb = 0; cb < 8; ++cb) {
            const int c = cb * 32 + l31;
            const int ch0 = (0 + h) ^ ((c >> 1) & 3);
            const int ch1 = (2 + h) ^ ((c >> 1) & 3);
            vreg[cb * 2]     = *reinterpret_cast<const short8*>(&Vlds[vslot][c * 32 + ch0 * 8]);
            vreg[cb * 2 + 1] = *reinterpret_cast<const short8*>(&Vlds[vslot][c * 32 + ch1 * 8]);
        }

        // drain K(it+1)+V(it+1) (keep V(it+2)'s 4) -> next barrier guarantees them landed
        asm volatile("s_waitcnt vmcnt(4)" ::: "memory");
        __builtin_amdgcn_sched_barrier(0);
    };

    // prologue: K(0), V(0), V(1); drain K(0)+V(0), keep V(1) in flight
    kstage(0, 0); vstage(0, 0); vstage(1, 1);
    asm volatile("s_waitcnt vmcnt(4)" ::: "memory");

    PFrag paA0, paA1, paB0, paB1;
    paA0.u[0] = paA0.u[1] = paA0.u[2] = paA0.u[3] = 0;
    paA1 = paA0; paB0 = paA0; paB1 = paA0;

    #pragma unroll 1
    for (int io = 0; io < NIT / 2; ++io) {
        body(io * 2,     paA0, paA1, paB0, paB1);
        body(io * 2 + 1, paB0, paB1, paA0, paA1);
    }

    // ---- epilogue: PV(NIT-1) from registers, reduce lsum, store partials ----
    asm volatile("s_waitcnt vmcnt(0)" ::: "memory");
    #pragma unroll
    for (int cb = 0; cb < 8; ++cb) {
        oacc[cb] = __builtin_amdgcn_mfma_f32_32x32x16_bf16(vreg[cb * 2],     paA0.v, oacc[cb], 0, 0, 0);
        oacc[cb] = __builtin_amdgcn_mfma_f32_32x32x16_bf16(vreg[cb * 2 + 1], paA1.v, oacc[cb], 0, 0, 0);
    }
    float lt = lsum + __shfl_xor(lsum, 32);          // full row sum for this t-half
    float* dst = (th == 0) ? part0 : part1;
    if (lane < 32) lbuf[th * 16384 + n * 4096 + s0 + lane] = lt;
    float* on = dst + (size_t)n * C_CH * S_LEN;
    #pragma unroll
    for (int cb = 0; cb < 8; ++cb) {
        #pragma unroll
        for (int r = 0; r < 16; ++r) {
            const int c = cb * 32 + (r & 3) + 8 * (r >> 2) + 4 * h;
            on[(size_t)c * S_LEN + s0 + l31] = oacc[cb][r];
        }
    }
}

// ---------- kernel 5: combine t-halves: out = (p0 + p1) / (l0 + l1) ----------
__global__ void nlm_combine_kernel(float* __restrict__ out, const float* __restrict__ part1,
                                   const float* __restrict__ lbuf) {
    const size_t e0 = ((size_t)blockIdx.x * 256 + threadIdx.x) * 4;
    const int n = (int)(e0 >> 20);
    const int s = (int)(e0 & 4095);
    float4 o0 = *reinterpret_cast<const float4*>(out + e0);
    float4 o1 = *reinterpret_cast<const float4*>(part1 + e0);
    float4 l0 = *reinterpret_cast<const float4*>(lbuf + n * 4096 + s);
    float4 l1 = *reinterpret_cast<const float4*>(lbuf + 16384 + n * 4096 + s);
    float4 r;
    r.x = (o0.x + o1.x) / (l0.x + l1.x);
    r.y = (o0.y + o1.y) / (l0.y + l1.y);
    r.z = (o0.z + o1.z) / (l0.z + l1.z);
    r.w = (o0.w + o1.w) / (l0.w + l1.w);
    *reinterpret_cast<float4*>(out + e0) = r;
}

extern "C" void kernel_launch(void* const* d_in, const int* in_sizes, int n_in,
                              void* d_out, int out_size, void* d_ws, size_t ws_size,
                              hipStream_t stream) {
    const float* x  = (const float*)d_in[0];
    const float* tw = (const float*)d_in[1];
    const float* tb = (const float*)d_in[2];
    const float* pw = (const float*)d_in[3];
    const float* pb = (const float*)d_in[4];
    float* out = (float*)d_out;

    char* ws = (char*)d_ws;
    unsigned short* xb = (unsigned short*)(ws);               //  8,388,608 B
    unsigned short* Qb = (unsigned short*)(ws + 8388608);     //  4,194,304 B
    unsigned short* Kb = (unsigned short*)(ws + 12582912);    //  4,194,304 B
    unsigned short* wb = (unsigned short*)(ws + 16777216);    //    131,072 B
    float*          lb = (float*)(ws + 16908288);             //    131,072 B
    float*          p1 = (float*)(ws + 17039360);             // 16,777,216 B

    nlm_conv_kernel<<<4096, 256, 0, stream>>>(x, xb);
    nlm_wconv_kernel<<<64, 256, 0, stream>>>(tw, pw, wb);
    nlm_proj_kernel<<<dim3(64, 4), 256, 0, stream>>>(x, wb, tb, pb, Qb, Kb);
    nlm_attn_kernel<<<256, 256, 0, stream>>>(Qb, Kb, xb, out, p1, lb);
    nlm_combine_kernel<<<4096, 256, 0, stream>>>(out, p1, lb);
}